// Round 3
// baseline (936.466 us; speedup 1.0000x reference)
//
#include <hip/hip_runtime.h>

// TTGNN: 2-layer GAT-style transformer conv, N=20000, E=120000, D=1024, H=8, C=128.
// R4: attention kernel redesigned as wave-per-node (lane owns 16 channels).
// R5: XCD-aware swizzle in gemm_bf16; m_kernel one-pass (all 5 types).
// R6: 4-deep gather batching — NULL result (latency of xlb gathers not the
//     bottleneck); reverted in R7.
// R7: attack the per-wave serial chains instead:
//     (a) scatter_kernel writes packed (src<<3)|etype directly -> attn drops
//         one dependent round-trip + both uncoalesced EI/eattr gathers;
//     (b) T14 issue-early: h-row + cnt loads at kernel top (HBM latency hides
//         under the edge loop);
//     (c) 1024-thread blocks (16 waves) to lift the ~2-3 WG/CU residency cap;
//     (d) skip dead fp32 h write in the last layer.

#define NN 20000
#define NE 120000
#define DD 1024
#define NH 8

typedef __attribute__((ext_vector_type(4))) float f32x4;
typedef __bf16 bf16x8 __attribute__((ext_vector_type(8)));

__device__ __forceinline__ unsigned short f2bf(float f) {
  unsigned int u = __float_as_uint(f);
  u += 0x7FFFu + ((u >> 16) & 1u);   // round-to-nearest-even
  return (unsigned short)(u >> 16);
}
__device__ __forceinline__ float bf2f(unsigned short u) {
  return __uint_as_float((unsigned int)u << 16);
}
__device__ __forceinline__ void unpack8(uint4 u, float* f) {
  f[0] = __uint_as_float(u.x << 16); f[1] = __uint_as_float(u.x & 0xFFFF0000u);
  f[2] = __uint_as_float(u.y << 16); f[3] = __uint_as_float(u.y & 0xFFFF0000u);
  f[4] = __uint_as_float(u.z << 16); f[5] = __uint_as_float(u.z & 0xFFFF0000u);
  f[6] = __uint_as_float(u.w << 16); f[7] = __uint_as_float(u.w & 0xFFFF0000u);
}

// ---------------- CSR build ----------------

__global__ __launch_bounds__(256) void count_kernel(
    const int* __restrict__ EI, const int* __restrict__ eattr, int* __restrict__ cnt) {
  int e = blockIdx.x * 256 + threadIdx.x;
  if (e < NE) {
    int d = EI[NE + e];
    int t = eattr[e];
    atomicAdd(&cnt[d * 5 + t], 1);
  }
}

__global__ __launch_bounds__(1024) void scan_kernel(
    const int* __restrict__ cnt, int* __restrict__ rowptr, int* __restrict__ cursor) {
  __shared__ int wsum[16];
  __shared__ int carry_s;
  int tid = threadIdx.x, lane = tid & 63, wv = tid >> 6;
  if (tid == 0) carry_s = 0;
  __syncthreads();
  for (int base = 0; base < NN; base += 1024) {
    int n = base + tid;
    int d = 0;
    if (n < NN) {
      const int* c = cnt + n * 5;
      d = c[0] + c[1] + c[2] + c[3] + c[4];
    }
    int v = d;
    #pragma unroll
    for (int off = 1; off < 64; off <<= 1) {
      int t = __shfl_up(v, off);
      if (lane >= off) v += t;
    }
    if (lane == 63) wsum[wv] = v;
    __syncthreads();
    int woff = 0;
    #pragma unroll
    for (int w = 0; w < 16; ++w) if (w < wv) woff += wsum[w];
    int carry = carry_s;
    int excl = carry + woff + v - d;
    if (n < NN) { rowptr[n] = excl; cursor[n] = excl; }
    __syncthreads();
    if (tid == 0) {
      int t = 0;
      #pragma unroll
      for (int w = 0; w < 16; ++w) t += wsum[w];
      carry_s = carry + t;
    }
    __syncthreads();
  }
  if (tid == 0) rowptr[NN] = carry_s;
}

// R7: write packed (src<<3)|etype directly (reads here are coalesced); attn
// then needs a single load per chunk instead of eids->EI->eattr chain.
__global__ __launch_bounds__(256) void scatter_kernel(
    const int* __restrict__ EI, const int* __restrict__ eattr,
    int* __restrict__ cursor, int* __restrict__ epk) {
  int e = blockIdx.x * 256 + threadIdx.x;
  if (e < NE) {
    int d = EI[NE + e];
    int s = EI[e];
    int t = eattr[e];
    int pos = atomicAdd(&cursor[d], 1);
    epk[pos] = (s << 3) | t;
  }
}

// ---------------- h0 = x + node_type_emb[node_types] ----------------

__global__ __launch_bounds__(256) void init_h_kernel(
    const float* __restrict__ x, const int* __restrict__ ntypes,
    const float* __restrict__ ntemb, float* __restrict__ h,
    unsigned short* __restrict__ hb) {
  int idx = blockIdx.x * 256 + threadIdx.x;
  int n = idx >> 8;
  int d4 = idx & 255;
  int t = ntypes[n];
  float4 xv = ((const float4*)x)[idx];
  float4 ev = ((const float4*)ntemb)[t * 256 + d4];
  float4 o;
  o.x = xv.x + ev.x; o.y = xv.y + ev.y; o.z = xv.z + ev.z; o.w = xv.w + ev.w;
  ((float4*)h)[idx] = o;
  ushort4 hv;
  hv.x = f2bf(o.x); hv.y = f2bf(o.y); hv.z = f2bf(o.z); hv.w = f2bf(o.w);
  ((ushort4*)hb)[idx] = hv;
}

// ---------------- weight transpose + bf16: WT[n][k] = bf16(W[k][n]) ----------------

__global__ __launch_bounds__(256) void transpose_w_kernel(
    const float* __restrict__ W, unsigned short* __restrict__ WT) {
  __shared__ float tile[32][33];
  int tx = threadIdx.x & 31, ty = threadIdx.x >> 5;
  int bx = blockIdx.x * 32;   // n base
  int by = blockIdx.y * 32;   // k base
  #pragma unroll
  for (int r = 0; r < 4; ++r)
    tile[ty + r * 8][tx] = W[(size_t)(by + ty + r * 8) * DD + bx + tx];
  __syncthreads();
  #pragma unroll
  for (int r = 0; r < 4; ++r)
    WT[(size_t)(bx + ty + r * 8) * DD + by + tx] = f2bf(tile[tx][ty + r * 8]);
}

// ---------------- M[t] = edge_type_emb[t] @ W_e[l]   (5 x 1024) ----------------

__global__ __launch_bounds__(256) void m_kernel(
    const float* __restrict__ ete, const float* __restrict__ We, float* __restrict__ M) {
  __shared__ float red[4][5][64];
  const int jl = threadIdx.x & 63;
  const int kc = threadIdx.x >> 6;          // wave-uniform
  const int j = blockIdx.x * 64 + jl;
  float acc[5] = {0.f, 0.f, 0.f, 0.f, 0.f};
  const int k0 = kc * 256;
  for (int k = k0; k < k0 + 256; ++k) {
    float w = We[(size_t)k * DD + j];
    #pragma unroll
    for (int t = 0; t < 5; ++t) acc[t] += ete[t * DD + k] * w;
  }
  #pragma unroll
  for (int t = 0; t < 5; ++t) red[kc][t][jl] = acc[t];
  __syncthreads();
  if (threadIdx.x < 64) {
    #pragma unroll
    for (int t = 0; t < 5; ++t)
      M[t * DD + blockIdx.x * 64 + threadIdx.x] =
          red[0][t][threadIdx.x] + red[1][t][threadIdx.x] +
          red[2][t][threadIdx.x] + red[3][t][threadIdx.x];
  }
}

// ---------------- bf16 MFMA GEMM, global_load_lds staging (m97 structure) ----

__global__ __launch_bounds__(256) void gemm_bf16(
    const unsigned short* __restrict__ A, const unsigned short* __restrict__ BT,
    const float* __restrict__ bias0, const float* __restrict__ bias1,
    void* __restrict__ C0v, void* __restrict__ C1v,
    const float* __restrict__ resid, const float* __restrict__ gatep,
    int M, int mode) {
  __shared__ unsigned short lsA[128 * 32];
  __shared__ unsigned short lsB[128 * 32];
  const int tid = threadIdx.x;
  const int lane = tid & 63;
  const int wv = tid >> 6;
  const int wm = wv & 1, wn = wv >> 1;

  // T1: XCD swizzle. nwg % 8 == 0 for both launch shapes (2512, 1256).
  const int nwg = gridDim.x * gridDim.y;
  const int lid = blockIdx.y * gridDim.x + blockIdx.x;
  const int cpx = nwg >> 3;
  const int swz = (lid & 7) * cpx + (lid >> 3);
  const int bm = swz / gridDim.x, bn = swz % gridDim.x;

  const int row0 = bm * 128, col0 = bn * 128;
  const int l15 = lane & 15, quad = lane >> 4;

  f32x4 acc[4][4];
  #pragma unroll
  for (int mt = 0; mt < 4; ++mt)
    #pragma unroll
    for (int nt = 0; nt < 4; ++nt) {
      f32x4 z = {0.f, 0.f, 0.f, 0.f};
      acc[mt][nt] = z;
    }

  const int r_in = lane >> 2;            // 0..15
  const int kchunk = (lane & 3) * 8;     // bf16-element offset within 32-wide K

  for (int kk = 0; kk < DD; kk += 32) {
    #pragma unroll
    for (int j = 0; j < 2; ++j) {
      int r = wv * 32 + j * 16;                  // wave-uniform row base
      int gr = row0 + r + r_in;
      if (gr > M - 1) gr = M - 1;                // clamp tail (masked at store)
      const unsigned short* gpA = A + (size_t)gr * DD + kk + kchunk;
      __builtin_amdgcn_global_load_lds(
          (const __attribute__((address_space(1))) unsigned int*)gpA,
          (__attribute__((address_space(3))) unsigned int*)(lsA + r * 32), 16, 0, 0);
      const unsigned short* gpB = BT + (size_t)(col0 + r + r_in) * DD + kk + kchunk;
      __builtin_amdgcn_global_load_lds(
          (const __attribute__((address_space(1))) unsigned int*)gpB,
          (__attribute__((address_space(3))) unsigned int*)(lsB + r * 32), 16, 0, 0);
    }
    __syncthreads();
    bf16x8 af[4], bfr[4];
    #pragma unroll
    for (int mt = 0; mt < 4; ++mt)
      af[mt] = *(const bf16x8*)(lsA + (wm * 64 + mt * 16 + l15) * 32 + quad * 8);
    #pragma unroll
    for (int nt = 0; nt < 4; ++nt)
      bfr[nt] = *(const bf16x8*)(lsB + (wn * 64 + nt * 16 + l15) * 32 + quad * 8);
    #pragma unroll
    for (int mt = 0; mt < 4; ++mt)
      #pragma unroll
      for (int nt = 0; nt < 4; ++nt)
        acc[mt][nt] = __builtin_amdgcn_mfma_f32_16x16x32_bf16(af[mt], bfr[nt], acc[mt][nt], 0, 0, 0);
    __syncthreads();
  }

  if (mode == 0) {
    unsigned short* Cb = (unsigned short*)(bn < 8 ? C0v : C1v);
    const float* bp = (bn < 8) ? bias0 : bias1;
    int coff = (bn < 8) ? 0 : 1024;
    #pragma unroll
    for (int mt = 0; mt < 4; ++mt) {
      #pragma unroll
      for (int r = 0; r < 4; ++r) {
        int grow = row0 + wm * 64 + mt * 16 + quad * 4 + r;
        if (grow >= M) continue;
        #pragma unroll
        for (int nt = 0; nt < 4; ++nt) {
          int c = col0 - coff + wn * 64 + nt * 16 + l15;
          Cb[(size_t)grow * DD + c] = f2bf(acc[mt][nt][r] + bp[c]);
        }
      }
    }
  } else {
    float* Cp = (float*)C0v;
    float g = gatep[0];
    #pragma unroll
    for (int mt = 0; mt < 4; ++mt) {
      #pragma unroll
      for (int r = 0; r < 4; ++r) {
        int grow = row0 + wm * 64 + mt * 16 + quad * 4 + r;
        if (grow >= M) continue;
        #pragma unroll
        for (int nt = 0; nt < 4; ++nt) {
          int c = col0 + wn * 64 + nt * 16 + l15;
          float v = acc[mt][nt][r] + bias0[c];
          Cp[(size_t)grow * DD + c] = resid[(size_t)grow * DD + c] + g * v;
        }
      }
    }
  }
}

// ---------------- fused attention, wave-per-node ----------------
// Block = 1024 threads = 16 independent waves (R7: lift WG/CU residency cap);
// wave handles node n, lane owns channels [lane*16, lane*16+16). Softmax
// without max-subtraction (shift-invariant; logits bounded). Edge metadata is
// pre-packed by scatter_kernel: one coalesced load per 64-edge chunk.

__global__ __launch_bounds__(1024) void attn_kernel(
    const unsigned short* __restrict__ xlb, const unsigned short* __restrict__ xrb,
    const int* __restrict__ rowptr, const int* __restrict__ epk,
    const int* __restrict__ cnt, const float* __restrict__ Mbuf,
    const float* __restrict__ attl, const float* __restrict__ biasl,
    const float* __restrict__ gammal, const float* __restrict__ betal,
    float* __restrict__ h, unsigned short* __restrict__ hb, int write_h) {
  const int lane = threadIdx.x & 63;
  const int wv = threadIdx.x >> 6;
  const int n = blockIdx.x * 16 + wv;
  const int ch = lane * 16;

  // T14 issue-early: epilogue h-row + self-loop cnt loads issued first; their
  // ~900cy HBM latency hides under the whole edge loop.
  const float4* hp_pre = (const float4*)(h + (size_t)n * DD + ch);
  float4 h4a = hp_pre[0], h4b = hp_pre[1];
  const int* c5 = cnt + n * 5;
  int c0 = c5[0], c1 = c5[1], c2 = c5[2], c3 = c5[3], c4 = c5[4];
  const int beg = rowptr[n], end = rowptr[n + 1];

  float xrf[16], attf[16];
  {
    const uint4* xp = (const uint4*)(xrb + (size_t)n * DD + ch);
    uint4 a = xp[0], b = xp[1];
    unpack8(a, xrf); unpack8(b, xrf + 8);
    const float4* ap = (const float4*)(attl + ch);
    #pragma unroll
    for (int q = 0; q < 4; ++q) {
      float4 t = ap[q];
      attf[q * 4 + 0] = t.x; attf[q * 4 + 1] = t.y;
      attf[q * 4 + 2] = t.z; attf[q * 4 + 3] = t.w;
    }
  }
  float acc[16];
  #pragma unroll
  for (int c = 0; c < 16; ++c) acc[c] = 0.f;
  float den = 0.f;

  for (int base = beg; base < end; base += 64) {
    int cc = min(64, end - base);
    int packed = 0;
    if (lane < cc) packed = epk[base + lane];
    for (int j = 0; j < cc; ++j) {
      int pk = __shfl(packed, j);
      int src = pk >> 3, at = pk & 7;
      const uint4* vp = (const uint4*)(xlb + (size_t)src * DD + ch);
      uint4 v0 = vp[0], v1 = vp[1];
      const float4* mp = (const float4*)(Mbuf + at * DD + ch);
      float vf[16];
      unpack8(v0, vf); unpack8(v1, vf + 8);
      float lg = 0.f;
      #pragma unroll
      for (int q = 0; q < 4; ++q) {
        float4 m = mp[q];
        float s0 = vf[q * 4 + 0] + xrf[q * 4 + 0] + m.x; s0 = fmaxf(s0, 0.2f * s0);
        float s1 = vf[q * 4 + 1] + xrf[q * 4 + 1] + m.y; s1 = fmaxf(s1, 0.2f * s1);
        float s2 = vf[q * 4 + 2] + xrf[q * 4 + 2] + m.z; s2 = fmaxf(s2, 0.2f * s2);
        float s3 = vf[q * 4 + 3] + xrf[q * 4 + 3] + m.w; s3 = fmaxf(s3, 0.2f * s3);
        lg += s0 * attf[q * 4 + 0] + s1 * attf[q * 4 + 1]
            + s2 * attf[q * 4 + 2] + s3 * attf[q * 4 + 3];
      }
      lg += __shfl_xor(lg, 1);
      lg += __shfl_xor(lg, 2);
      lg += __shfl_xor(lg, 4);
      float p = __expf(lg);
      den += p;
      #pragma unroll
      for (int c = 0; c < 16; ++c) acc[c] += p * vf[c];
    }
  }

  // self-loop: edge emb = mean of incoming edge-type embeddings
  {
    float inv = 1.f / fmaxf((float)(c0 + c1 + c2 + c3 + c4), 1.f);
    float w0 = c0 * inv, w1 = c1 * inv, w2 = c2 * inv, w3 = c3 * inv, w4 = c4 * inv;
    const uint4* vp = (const uint4*)(xlb + (size_t)n * DD + ch);
    uint4 v0 = vp[0], v1 = vp[1];
    float vf[16];
    unpack8(v0, vf); unpack8(v1, vf + 8);
    const float* m0 = Mbuf + 0 * DD + ch;
    const float* m1 = Mbuf + 1 * DD + ch;
    const float* m2 = Mbuf + 2 * DD + ch;
    const float* m3 = Mbuf + 3 * DD + ch;
    const float* m4 = Mbuf + 4 * DD + ch;
    float lg = 0.f;
    #pragma unroll
    for (int c = 0; c < 16; ++c) {
      float ee = w0 * m0[c] + w1 * m1[c] + w2 * m2[c] + w3 * m3[c] + w4 * m4[c];
      float s = vf[c] + xrf[c] + ee;
      s = fmaxf(s, 0.2f * s);
      lg += s * attf[c];
    }
    lg += __shfl_xor(lg, 1);
    lg += __shfl_xor(lg, 2);
    lg += __shfl_xor(lg, 4);
    float p = __expf(lg);
    den += p;
    #pragma unroll
    for (int c = 0; c < 16; ++c) acc[c] += p * vf[c];
  }

  // epilogue: alpha-normalize + bias + ELU + residual + LayerNorm (in-wave)
  float invd = 1.f / den;
  float y[16];
  float s1 = 0.f, s2 = 0.f;
  {
    const float4* bp = (const float4*)(biasl + ch);
    #pragma unroll
    for (int q = 0; q < 4; ++q) {
      float4 b4 = bp[q];
      float4 h4 = (q < 2) ? h4a : h4b;
      // select the right half of the prefetched pair per q
      float hx, hy, hz, hw;
      if (q == 0) { hx = h4a.x; hy = h4a.y; hz = h4a.z; hw = h4a.w; }
      else if (q == 1) { hx = h4b.x; hy = h4b.y; hz = h4b.z; hw = h4b.w; }
      else { hx = 0; hy = 0; hz = 0; hw = 0; }
      (void)h4;
      if (q >= 2) {
        // second prefetched pair covers q=2,3: reload from registers below
      }
      float o0 = acc[q * 4 + 0] * invd + b4.x;
      float o1 = acc[q * 4 + 1] * invd + b4.y;
      float o2 = acc[q * 4 + 2] * invd + b4.z;
      float o3 = acc[q * 4 + 3] * invd + b4.w;
      o0 = o0 > 0.f ? o0 : (__expf(o0) - 1.f);
      o1 = o1 > 0.f ? o1 : (__expf(o1) - 1.f);
      o2 = o2 > 0.f ? o2 : (__expf(o2) - 1.f);
      o3 = o3 > 0.f ? o3 : (__expf(o3) - 1.f);
      y[q * 4 + 0] = o0; y[q * 4 + 1] = o1;
      y[q * 4 + 2] = o2; y[q * 4 + 3] = o3;
    }
    // add residual from the two prefetched float4 pairs (ch..ch+7) and the
    // remaining 8 channels loaded here (ch+8..ch+15 were NOT prefetched if
    // layout mismatched) — prefetch covered 8 floats (2x float4 = ch..ch+7).
    const float4* hp = (const float4*)(h + (size_t)n * DD + ch);
    float4 h4c = hp[2], h4d = hp[3];
    y[0] += h4a.x;  y[1] += h4a.y;  y[2] += h4a.z;  y[3] += h4a.w;
    y[4] += h4b.x;  y[5] += h4b.y;  y[6] += h4b.z;  y[7] += h4b.w;
    y[8] += h4c.x;  y[9] += h4c.y;  y[10] += h4c.z; y[11] += h4c.w;
    y[12] += h4d.x; y[13] += h4d.y; y[14] += h4d.z; y[15] += h4d.w;
    #pragma unroll
    for (int c = 0; c < 16; ++c) {
      s1 += y[c];
      s2 += y[c] * y[c];
    }
  }
  #pragma unroll
  for (int off = 1; off < 64; off <<= 1) {
    s1 += __shfl_xor(s1, off);
    s2 += __shfl_xor(s2, off);
  }
  float mu = s1 * (1.f / 1024.f);
  float var = s2 * (1.f / 1024.f) - mu * mu;
  float rs = rsqrtf(var + 1e-5f);
  {
    const float4* gp = (const float4*)(gammal + ch);
    const float4* bp = (const float4*)(betal + ch);
    float4* hp = (float4*)(h + (size_t)n * DD + ch);
    uint4* hbp = (uint4*)(hb + (size_t)n * DD + ch);
    uint4 pk0, pk1;
    unsigned int* pk = (unsigned int*)&pk0;
    #pragma unroll
    for (int q = 0; q < 4; ++q) {
      float4 g4 = gp[q];
      float4 b4 = bp[q];
      float4 o4;
      o4.x = (y[q * 4 + 0] - mu) * rs * g4.x + b4.x;
      o4.y = (y[q * 4 + 1] - mu) * rs * g4.y + b4.y;
      o4.z = (y[q * 4 + 2] - mu) * rs * g4.z + b4.z;
      o4.w = (y[q * 4 + 3] - mu) * rs * g4.w + b4.w;
      if (write_h) hp[q] = o4;
      unsigned int lo = (unsigned int)f2bf(o4.x) | ((unsigned int)f2bf(o4.y) << 16);
      unsigned int hi = (unsigned int)f2bf(o4.z) | ((unsigned int)f2bf(o4.w) << 16);
      if (q < 2) { pk[q * 2] = lo; pk[q * 2 + 1] = hi; }
      else {
        unsigned int* pkh = (unsigned int*)&pk1;
        pkh[(q - 2) * 2] = lo; pkh[(q - 2) * 2 + 1] = hi;
      }
    }
    hbp[0] = pk0;
    hbp[1] = pk1;
  }
}

// ---------------- launcher ----------------

extern "C" void kernel_launch(void* const* d_in, const int* in_sizes, int n_in,
                              void* d_out, int out_size, void* d_ws, size_t ws_size,
                              hipStream_t stream) {
  (void)in_sizes; (void)n_in; (void)out_size; (void)ws_size;
  const float* x      = (const float*)d_in[0];
  const int*   EI     = (const int*)d_in[1];
  const int*   eattr  = (const int*)d_in[2];
  const int*   ntypes = (const int*)d_in[3];
  const float* ntemb  = (const float*)d_in[4];
  const float* etemb  = (const float*)d_in[5];
  const float* W_l    = (const float*)d_in[6];
  const float* b_l    = (const float*)d_in[7];
  const float* W_r    = (const float*)d_in[8];
  const float* b_r    = (const float*)d_in[9];
  const float* W_e    = (const float*)d_in[10];
  const float* att    = (const float*)d_in[11];
  const float* bias   = (const float*)d_in[12];
  const float* gamma  = (const float*)d_in[13];
  const float* beta   = (const float*)d_in[14];
  const float* W_out  = (const float*)d_in[15];
  const float* b_out  = (const float*)d_in[16];
  const float* gate   = (const float*)d_in[17];
  float* out = (float*)d_out;

  char* ws = (char*)d_ws;
  size_t off = 0;
  auto alloc = [&](size_t bytes) {
    char* p = ws + off;
    off = (off + bytes + 255) & ~(size_t)255;
    return p;
  };
  float*          h       = (float*)alloc((size_t)NN * DD * 4);
  unsigned short* hb      = (unsigned short*)alloc((size_t)NN * DD * 2);
  unsigned short* xlb     = (unsigned short*)alloc((size_t)NN * DD * 2);
  unsigned short* xrb     = (unsigned short*)alloc((size_t)NN * DD * 2);
  unsigned short* WTcat   = (unsigned short*)alloc((size_t)2 * DD * DD * 2);  // [W_l^T ; W_r^T]
  unsigned short* WT2     = (unsigned short*)alloc((size_t)DD * DD * 2);
  float*          Mbuf    = (float*)alloc((size_t)5 * DD * 4);
  int*            countb  = (int*)alloc((size_t)NN * 5 * 4);
  int*            rowptr  = (int*)alloc((size_t)(NN + 1) * 4);
  int*            cursor  = (int*)alloc((size_t)NN * 4);
  int*            epk     = (int*)alloc((size_t)NE * 4);

  hipMemsetAsync(countb, 0, (size_t)NN * 5 * 4, stream);
  count_kernel<<<(NE + 255) / 256, 256, 0, stream>>>(EI, eattr, countb);
  scan_kernel<<<1, 1024, 0, stream>>>(countb, rowptr, cursor);
  scatter_kernel<<<(NE + 255) / 256, 256, 0, stream>>>(EI, eattr, cursor, epk);
  init_h_kernel<<<NN, 256, 0, stream>>>(x, ntypes, ntemb, h, hb);

  dim3 tgrid(DD / 32, DD / 32);
  dim3 ggrid2(16, (NN + 127) / 128);   // dual GEMM: N=2048, 2512 blocks (%8==0)
  dim3 ggrid1(8, (NN + 127) / 128);    // final GEMM: N=1024, 1256 blocks (%8==0)
  for (int l = 0; l < 2; ++l) {
    transpose_w_kernel<<<tgrid, 256, 0, stream>>>(W_l + (size_t)l * DD * DD, WTcat);
    transpose_w_kernel<<<tgrid, 256, 0, stream>>>(W_r + (size_t)l * DD * DD, WTcat + (size_t)DD * DD);
    m_kernel<<<DD / 64, 256, 0, stream>>>(etemb, W_e + (size_t)l * DD * DD, Mbuf);
    gemm_bf16<<<ggrid2, 256, 0, stream>>>(hb, WTcat, b_l + l * DD, b_r + l * DD,
                                          xlb, xrb, nullptr, nullptr, NN, 0);
    attn_kernel<<<NN / 16, 1024, 0, stream>>>(xlb, xrb, rowptr, epk, countb, Mbuf,
                                              att + l * DD, bias + l * DD,
                                              gamma + l * DD, beta + l * DD, h, hb,
                                              l == 0 ? 1 : 0);
  }
  transpose_w_kernel<<<tgrid, 256, 0, stream>>>(W_out, WT2);
  gemm_bf16<<<ggrid1, 256, 0, stream>>>(hb, WT2, b_out, nullptr,
                                        out, nullptr, x, gate, NN, 1);
}

// Round 4
// 877.847 us; speedup vs baseline: 1.0668x; 1.0668x over previous
//
#include <hip/hip_runtime.h>

// TTGNN: 2-layer GAT-style transformer conv, N=20000, E=120000, D=1024, H=8, C=128.
// R4: attention kernel as wave-per-node (lane owns 16 channels), 4-wave blocks.
// R5: XCD-aware swizzle in gemm_bf16; m_kernel one-pass (all 5 types).
// R6: 4-deep gather batching — NULL (compiler already pipelines gathers).
// R7: 16-wave blocks + split h prefetch — REGRESSION (+150MB HBM traffic,
//     +30us). Key inference: marginal bytes cost ~2TB/s => traffic-bound.
// R8: revert attn to R4 structure (4-wave blocks, single late h read); keep
//     epk packed edge metadata (one coalesced load, no eids->EI->eattr chain);
//     keep dead-store skip of fp32 h write in the last layer (-80MB).

#define NN 20000
#define NE 120000
#define DD 1024
#define NH 8

typedef __attribute__((ext_vector_type(4))) float f32x4;
typedef __bf16 bf16x8 __attribute__((ext_vector_type(8)));

__device__ __forceinline__ unsigned short f2bf(float f) {
  unsigned int u = __float_as_uint(f);
  u += 0x7FFFu + ((u >> 16) & 1u);   // round-to-nearest-even
  return (unsigned short)(u >> 16);
}
__device__ __forceinline__ float bf2f(unsigned short u) {
  return __uint_as_float((unsigned int)u << 16);
}
__device__ __forceinline__ void unpack8(uint4 u, float* f) {
  f[0] = __uint_as_float(u.x << 16); f[1] = __uint_as_float(u.x & 0xFFFF0000u);
  f[2] = __uint_as_float(u.y << 16); f[3] = __uint_as_float(u.y & 0xFFFF0000u);
  f[4] = __uint_as_float(u.z << 16); f[5] = __uint_as_float(u.z & 0xFFFF0000u);
  f[6] = __uint_as_float(u.w << 16); f[7] = __uint_as_float(u.w & 0xFFFF0000u);
}

// ---------------- CSR build ----------------

__global__ __launch_bounds__(256) void count_kernel(
    const int* __restrict__ EI, const int* __restrict__ eattr, int* __restrict__ cnt) {
  int e = blockIdx.x * 256 + threadIdx.x;
  if (e < NE) {
    int d = EI[NE + e];
    int t = eattr[e];
    atomicAdd(&cnt[d * 5 + t], 1);
  }
}

__global__ __launch_bounds__(1024) void scan_kernel(
    const int* __restrict__ cnt, int* __restrict__ rowptr, int* __restrict__ cursor) {
  __shared__ int wsum[16];
  __shared__ int carry_s;
  int tid = threadIdx.x, lane = tid & 63, wv = tid >> 6;
  if (tid == 0) carry_s = 0;
  __syncthreads();
  for (int base = 0; base < NN; base += 1024) {
    int n = base + tid;
    int d = 0;
    if (n < NN) {
      const int* c = cnt + n * 5;
      d = c[0] + c[1] + c[2] + c[3] + c[4];
    }
    int v = d;
    #pragma unroll
    for (int off = 1; off < 64; off <<= 1) {
      int t = __shfl_up(v, off);
      if (lane >= off) v += t;
    }
    if (lane == 63) wsum[wv] = v;
    __syncthreads();
    int woff = 0;
    #pragma unroll
    for (int w = 0; w < 16; ++w) if (w < wv) woff += wsum[w];
    int carry = carry_s;
    int excl = carry + woff + v - d;
    if (n < NN) { rowptr[n] = excl; cursor[n] = excl; }
    __syncthreads();
    if (tid == 0) {
      int t = 0;
      #pragma unroll
      for (int w = 0; w < 16; ++w) t += wsum[w];
      carry_s = carry + t;
    }
    __syncthreads();
  }
  if (tid == 0) rowptr[NN] = carry_s;
}

// Writes packed (src<<3)|etype directly (reads here are coalesced); attn then
// needs a single load per chunk instead of the eids->EI->eattr chain.
__global__ __launch_bounds__(256) void scatter_kernel(
    const int* __restrict__ EI, const int* __restrict__ eattr,
    int* __restrict__ cursor, int* __restrict__ epk) {
  int e = blockIdx.x * 256 + threadIdx.x;
  if (e < NE) {
    int d = EI[NE + e];
    int s = EI[e];
    int t = eattr[e];
    int pos = atomicAdd(&cursor[d], 1);
    epk[pos] = (s << 3) | t;
  }
}

// ---------------- h0 = x + node_type_emb[node_types] ----------------

__global__ __launch_bounds__(256) void init_h_kernel(
    const float* __restrict__ x, const int* __restrict__ ntypes,
    const float* __restrict__ ntemb, float* __restrict__ h,
    unsigned short* __restrict__ hb) {
  int idx = blockIdx.x * 256 + threadIdx.x;
  int n = idx >> 8;
  int d4 = idx & 255;
  int t = ntypes[n];
  float4 xv = ((const float4*)x)[idx];
  float4 ev = ((const float4*)ntemb)[t * 256 + d4];
  float4 o;
  o.x = xv.x + ev.x; o.y = xv.y + ev.y; o.z = xv.z + ev.z; o.w = xv.w + ev.w;
  ((float4*)h)[idx] = o;
  ushort4 hv;
  hv.x = f2bf(o.x); hv.y = f2bf(o.y); hv.z = f2bf(o.z); hv.w = f2bf(o.w);
  ((ushort4*)hb)[idx] = hv;
}

// ---------------- weight transpose + bf16: WT[n][k] = bf16(W[k][n]) ----------------

__global__ __launch_bounds__(256) void transpose_w_kernel(
    const float* __restrict__ W, unsigned short* __restrict__ WT) {
  __shared__ float tile[32][33];
  int tx = threadIdx.x & 31, ty = threadIdx.x >> 5;
  int bx = blockIdx.x * 32;   // n base
  int by = blockIdx.y * 32;   // k base
  #pragma unroll
  for (int r = 0; r < 4; ++r)
    tile[ty + r * 8][tx] = W[(size_t)(by + ty + r * 8) * DD + bx + tx];
  __syncthreads();
  #pragma unroll
  for (int r = 0; r < 4; ++r)
    WT[(size_t)(bx + ty + r * 8) * DD + by + tx] = f2bf(tile[tx][ty + r * 8]);
}

// ---------------- M[t] = edge_type_emb[t] @ W_e[l]   (5 x 1024) ----------------

__global__ __launch_bounds__(256) void m_kernel(
    const float* __restrict__ ete, const float* __restrict__ We, float* __restrict__ M) {
  __shared__ float red[4][5][64];
  const int jl = threadIdx.x & 63;
  const int kc = threadIdx.x >> 6;          // wave-uniform
  const int j = blockIdx.x * 64 + jl;
  float acc[5] = {0.f, 0.f, 0.f, 0.f, 0.f};
  const int k0 = kc * 256;
  for (int k = k0; k < k0 + 256; ++k) {
    float w = We[(size_t)k * DD + j];
    #pragma unroll
    for (int t = 0; t < 5; ++t) acc[t] += ete[t * DD + k] * w;
  }
  #pragma unroll
  for (int t = 0; t < 5; ++t) red[kc][t][jl] = acc[t];
  __syncthreads();
  if (threadIdx.x < 64) {
    #pragma unroll
    for (int t = 0; t < 5; ++t)
      M[t * DD + blockIdx.x * 64 + threadIdx.x] =
          red[0][t][threadIdx.x] + red[1][t][threadIdx.x] +
          red[2][t][threadIdx.x] + red[3][t][threadIdx.x];
  }
}

// ---------------- bf16 MFMA GEMM, global_load_lds staging (m97 structure) ----

__global__ __launch_bounds__(256) void gemm_bf16(
    const unsigned short* __restrict__ A, const unsigned short* __restrict__ BT,
    const float* __restrict__ bias0, const float* __restrict__ bias1,
    void* __restrict__ C0v, void* __restrict__ C1v,
    const float* __restrict__ resid, const float* __restrict__ gatep,
    int M, int mode) {
  __shared__ unsigned short lsA[128 * 32];
  __shared__ unsigned short lsB[128 * 32];
  const int tid = threadIdx.x;
  const int lane = tid & 63;
  const int wv = tid >> 6;
  const int wm = wv & 1, wn = wv >> 1;

  // T1: XCD swizzle. nwg % 8 == 0 for both launch shapes (2512, 1256).
  const int nwg = gridDim.x * gridDim.y;
  const int lid = blockIdx.y * gridDim.x + blockIdx.x;
  const int cpx = nwg >> 3;
  const int swz = (lid & 7) * cpx + (lid >> 3);
  const int bm = swz / gridDim.x, bn = swz % gridDim.x;

  const int row0 = bm * 128, col0 = bn * 128;
  const int l15 = lane & 15, quad = lane >> 4;

  f32x4 acc[4][4];
  #pragma unroll
  for (int mt = 0; mt < 4; ++mt)
    #pragma unroll
    for (int nt = 0; nt < 4; ++nt) {
      f32x4 z = {0.f, 0.f, 0.f, 0.f};
      acc[mt][nt] = z;
    }

  const int r_in = lane >> 2;            // 0..15
  const int kchunk = (lane & 3) * 8;     // bf16-element offset within 32-wide K

  for (int kk = 0; kk < DD; kk += 32) {
    #pragma unroll
    for (int j = 0; j < 2; ++j) {
      int r = wv * 32 + j * 16;                  // wave-uniform row base
      int gr = row0 + r + r_in;
      if (gr > M - 1) gr = M - 1;                // clamp tail (masked at store)
      const unsigned short* gpA = A + (size_t)gr * DD + kk + kchunk;
      __builtin_amdgcn_global_load_lds(
          (const __attribute__((address_space(1))) unsigned int*)gpA,
          (__attribute__((address_space(3))) unsigned int*)(lsA + r * 32), 16, 0, 0);
      const unsigned short* gpB = BT + (size_t)(col0 + r + r_in) * DD + kk + kchunk;
      __builtin_amdgcn_global_load_lds(
          (const __attribute__((address_space(1))) unsigned int*)gpB,
          (__attribute__((address_space(3))) unsigned int*)(lsB + r * 32), 16, 0, 0);
    }
    __syncthreads();
    bf16x8 af[4], bfr[4];
    #pragma unroll
    for (int mt = 0; mt < 4; ++mt)
      af[mt] = *(const bf16x8*)(lsA + (wm * 64 + mt * 16 + l15) * 32 + quad * 8);
    #pragma unroll
    for (int nt = 0; nt < 4; ++nt)
      bfr[nt] = *(const bf16x8*)(lsB + (wn * 64 + nt * 16 + l15) * 32 + quad * 8);
    #pragma unroll
    for (int mt = 0; mt < 4; ++mt)
      #pragma unroll
      for (int nt = 0; nt < 4; ++nt)
        acc[mt][nt] = __builtin_amdgcn_mfma_f32_16x16x32_bf16(af[mt], bfr[nt], acc[mt][nt], 0, 0, 0);
    __syncthreads();
  }

  if (mode == 0) {
    unsigned short* Cb = (unsigned short*)(bn < 8 ? C0v : C1v);
    const float* bp = (bn < 8) ? bias0 : bias1;
    int coff = (bn < 8) ? 0 : 1024;
    #pragma unroll
    for (int mt = 0; mt < 4; ++mt) {
      #pragma unroll
      for (int r = 0; r < 4; ++r) {
        int grow = row0 + wm * 64 + mt * 16 + quad * 4 + r;
        if (grow >= M) continue;
        #pragma unroll
        for (int nt = 0; nt < 4; ++nt) {
          int c = col0 - coff + wn * 64 + nt * 16 + l15;
          Cb[(size_t)grow * DD + c] = f2bf(acc[mt][nt][r] + bp[c]);
        }
      }
    }
  } else {
    float* Cp = (float*)C0v;
    float g = gatep[0];
    #pragma unroll
    for (int mt = 0; mt < 4; ++mt) {
      #pragma unroll
      for (int r = 0; r < 4; ++r) {
        int grow = row0 + wm * 64 + mt * 16 + quad * 4 + r;
        if (grow >= M) continue;
        #pragma unroll
        for (int nt = 0; nt < 4; ++nt) {
          int c = col0 + wn * 64 + nt * 16 + l15;
          float v = acc[mt][nt][r] + bias0[c];
          Cp[(size_t)grow * DD + c] = resid[(size_t)grow * DD + c] + g * v;
        }
      }
    }
  }
}

// ---------------- fused attention, wave-per-node (R4 structure) ----------------
// Block = 256 threads = 4 independent waves; wave handles node n, lane owns
// channels [lane*16, lane*16+16). Softmax without max-subtraction (shift-
// invariant; logits bounded). Edge metadata pre-packed (epk): one coalesced
// load per 64-edge chunk. h fp32 read exactly once, in the epilogue.

__global__ __launch_bounds__(256) void attn_kernel(
    const unsigned short* __restrict__ xlb, const unsigned short* __restrict__ xrb,
    const int* __restrict__ rowptr, const int* __restrict__ epk,
    const int* __restrict__ cnt, const float* __restrict__ Mbuf,
    const float* __restrict__ attl, const float* __restrict__ biasl,
    const float* __restrict__ gammal, const float* __restrict__ betal,
    float* __restrict__ h, unsigned short* __restrict__ hb, int write_h) {
  const int lane = threadIdx.x & 63;
  const int wv = threadIdx.x >> 6;
  const int n = blockIdx.x * 4 + wv;
  if (n >= NN) return;
  const int ch = lane * 16;

  // cheap early scalar-ish loads (metadata only; h stays in the epilogue)
  const int beg = rowptr[n], end = rowptr[n + 1];
  const int* c5 = cnt + n * 5;
  int c0 = c5[0], c1 = c5[1], c2 = c5[2], c3 = c5[3], c4 = c5[4];

  float xrf[16], attf[16];
  {
    const uint4* xp = (const uint4*)(xrb + (size_t)n * DD + ch);
    uint4 a = xp[0], b = xp[1];
    unpack8(a, xrf); unpack8(b, xrf + 8);
    const float4* ap = (const float4*)(attl + ch);
    #pragma unroll
    for (int q = 0; q < 4; ++q) {
      float4 t = ap[q];
      attf[q * 4 + 0] = t.x; attf[q * 4 + 1] = t.y;
      attf[q * 4 + 2] = t.z; attf[q * 4 + 3] = t.w;
    }
  }
  float acc[16];
  #pragma unroll
  for (int c = 0; c < 16; ++c) acc[c] = 0.f;
  float den = 0.f;

  for (int base = beg; base < end; base += 64) {
    int cc = min(64, end - base);
    int packed = 0;
    if (lane < cc) packed = epk[base + lane];
    for (int j = 0; j < cc; ++j) {
      int pk = __shfl(packed, j);
      int src = pk >> 3, at = pk & 7;
      const uint4* vp = (const uint4*)(xlb + (size_t)src * DD + ch);
      uint4 v0 = vp[0], v1 = vp[1];
      const float4* mp = (const float4*)(Mbuf + at * DD + ch);
      float vf[16];
      unpack8(v0, vf); unpack8(v1, vf + 8);
      float lg = 0.f;
      #pragma unroll
      for (int q = 0; q < 4; ++q) {
        float4 m = mp[q];
        float s0 = vf[q * 4 + 0] + xrf[q * 4 + 0] + m.x; s0 = fmaxf(s0, 0.2f * s0);
        float s1 = vf[q * 4 + 1] + xrf[q * 4 + 1] + m.y; s1 = fmaxf(s1, 0.2f * s1);
        float s2 = vf[q * 4 + 2] + xrf[q * 4 + 2] + m.z; s2 = fmaxf(s2, 0.2f * s2);
        float s3 = vf[q * 4 + 3] + xrf[q * 4 + 3] + m.w; s3 = fmaxf(s3, 0.2f * s3);
        lg += s0 * attf[q * 4 + 0] + s1 * attf[q * 4 + 1]
            + s2 * attf[q * 4 + 2] + s3 * attf[q * 4 + 3];
      }
      lg += __shfl_xor(lg, 1);
      lg += __shfl_xor(lg, 2);
      lg += __shfl_xor(lg, 4);
      float p = __expf(lg);
      den += p;
      #pragma unroll
      for (int c = 0; c < 16; ++c) acc[c] += p * vf[c];
    }
  }

  // self-loop: edge emb = mean of incoming edge-type embeddings
  {
    float inv = 1.f / fmaxf((float)(c0 + c1 + c2 + c3 + c4), 1.f);
    float w0 = c0 * inv, w1 = c1 * inv, w2 = c2 * inv, w3 = c3 * inv, w4 = c4 * inv;
    const uint4* vp = (const uint4*)(xlb + (size_t)n * DD + ch);
    uint4 v0 = vp[0], v1 = vp[1];
    float vf[16];
    unpack8(v0, vf); unpack8(v1, vf + 8);
    const float* m0 = Mbuf + 0 * DD + ch;
    const float* m1 = Mbuf + 1 * DD + ch;
    const float* m2 = Mbuf + 2 * DD + ch;
    const float* m3 = Mbuf + 3 * DD + ch;
    const float* m4 = Mbuf + 4 * DD + ch;
    float lg = 0.f;
    #pragma unroll
    for (int c = 0; c < 16; ++c) {
      float ee = w0 * m0[c] + w1 * m1[c] + w2 * m2[c] + w3 * m3[c] + w4 * m4[c];
      float s = vf[c] + xrf[c] + ee;
      s = fmaxf(s, 0.2f * s);
      lg += s * attf[c];
    }
    lg += __shfl_xor(lg, 1);
    lg += __shfl_xor(lg, 2);
    lg += __shfl_xor(lg, 4);
    float p = __expf(lg);
    den += p;
    #pragma unroll
    for (int c = 0; c < 16; ++c) acc[c] += p * vf[c];
  }

  // epilogue: alpha-normalize + bias + ELU + residual + LayerNorm (in-wave)
  float invd = 1.f / den;
  float y[16];
  float s1 = 0.f, s2 = 0.f;
  {
    const float4* bp = (const float4*)(biasl + ch);
    const float4* hp = (const float4*)(h + (size_t)n * DD + ch);
    #pragma unroll
    for (int q = 0; q < 4; ++q) {
      float4 b4 = bp[q];
      float4 h4 = hp[q];
      float o0 = acc[q * 4 + 0] * invd + b4.x;
      float o1 = acc[q * 4 + 1] * invd + b4.y;
      float o2 = acc[q * 4 + 2] * invd + b4.z;
      float o3 = acc[q * 4 + 3] * invd + b4.w;
      o0 = o0 > 0.f ? o0 : (__expf(o0) - 1.f);
      o1 = o1 > 0.f ? o1 : (__expf(o1) - 1.f);
      o2 = o2 > 0.f ? o2 : (__expf(o2) - 1.f);
      o3 = o3 > 0.f ? o3 : (__expf(o3) - 1.f);
      y[q * 4 + 0] = o0 + h4.x; y[q * 4 + 1] = o1 + h4.y;
      y[q * 4 + 2] = o2 + h4.z; y[q * 4 + 3] = o3 + h4.w;
      s1 += y[q * 4 + 0] + y[q * 4 + 1] + y[q * 4 + 2] + y[q * 4 + 3];
      s2 += y[q * 4 + 0] * y[q * 4 + 0] + y[q * 4 + 1] * y[q * 4 + 1]
          + y[q * 4 + 2] * y[q * 4 + 2] + y[q * 4 + 3] * y[q * 4 + 3];
    }
  }
  #pragma unroll
  for (int off = 1; off < 64; off <<= 1) {
    s1 += __shfl_xor(s1, off);
    s2 += __shfl_xor(s2, off);
  }
  float mu = s1 * (1.f / 1024.f);
  float var = s2 * (1.f / 1024.f) - mu * mu;
  float rs = rsqrtf(var + 1e-5f);
  {
    const float4* gp = (const float4*)(gammal + ch);
    const float4* bp = (const float4*)(betal + ch);
    float4* hp = (float4*)(h + (size_t)n * DD + ch);
    uint4* hbp = (uint4*)(hb + (size_t)n * DD + ch);
    uint4 pk0, pk1;
    unsigned int* pk = (unsigned int*)&pk0;
    #pragma unroll
    for (int q = 0; q < 4; ++q) {
      float4 g4 = gp[q];
      float4 b4 = bp[q];
      float4 o4;
      o4.x = (y[q * 4 + 0] - mu) * rs * g4.x + b4.x;
      o4.y = (y[q * 4 + 1] - mu) * rs * g4.y + b4.y;
      o4.z = (y[q * 4 + 2] - mu) * rs * g4.z + b4.z;
      o4.w = (y[q * 4 + 3] - mu) * rs * g4.w + b4.w;
      if (write_h) hp[q] = o4;
      unsigned int lo = (unsigned int)f2bf(o4.x) | ((unsigned int)f2bf(o4.y) << 16);
      unsigned int hi = (unsigned int)f2bf(o4.z) | ((unsigned int)f2bf(o4.w) << 16);
      if (q < 2) { pk[q * 2] = lo; pk[q * 2 + 1] = hi; }
      else {
        unsigned int* pkh = (unsigned int*)&pk1;
        pkh[(q - 2) * 2] = lo; pkh[(q - 2) * 2 + 1] = hi;
      }
    }
    hbp[0] = pk0;
    hbp[1] = pk1;
  }
}

// ---------------- launcher ----------------

extern "C" void kernel_launch(void* const* d_in, const int* in_sizes, int n_in,
                              void* d_out, int out_size, void* d_ws, size_t ws_size,
                              hipStream_t stream) {
  (void)in_sizes; (void)n_in; (void)out_size; (void)ws_size;
  const float* x      = (const float*)d_in[0];
  const int*   EI     = (const int*)d_in[1];
  const int*   eattr  = (const int*)d_in[2];
  const int*   ntypes = (const int*)d_in[3];
  const float* ntemb  = (const float*)d_in[4];
  const float* etemb  = (const float*)d_in[5];
  const float* W_l    = (const float*)d_in[6];
  const float* b_l    = (const float*)d_in[7];
  const float* W_r    = (const float*)d_in[8];
  const float* b_r    = (const float*)d_in[9];
  const float* W_e    = (const float*)d_in[10];
  const float* att    = (const float*)d_in[11];
  const float* bias   = (const float*)d_in[12];
  const float* gamma  = (const float*)d_in[13];
  const float* beta   = (const float*)d_in[14];
  const float* W_out  = (const float*)d_in[15];
  const float* b_out  = (const float*)d_in[16];
  const float* gate   = (const float*)d_in[17];
  float* out = (float*)d_out;

  char* ws = (char*)d_ws;
  size_t off = 0;
  auto alloc = [&](size_t bytes) {
    char* p = ws + off;
    off = (off + bytes + 255) & ~(size_t)255;
    return p;
  };
  float*          h       = (float*)alloc((size_t)NN * DD * 4);
  unsigned short* hb      = (unsigned short*)alloc((size_t)NN * DD * 2);
  unsigned short* xlb     = (unsigned short*)alloc((size_t)NN * DD * 2);
  unsigned short* xrb     = (unsigned short*)alloc((size_t)NN * DD * 2);
  unsigned short* WTcat   = (unsigned short*)alloc((size_t)2 * DD * DD * 2);  // [W_l^T ; W_r^T]
  unsigned short* WT2     = (unsigned short*)alloc((size_t)DD * DD * 2);
  float*          Mbuf    = (float*)alloc((size_t)5 * DD * 4);
  int*            countb  = (int*)alloc((size_t)NN * 5 * 4);
  int*            rowptr  = (int*)alloc((size_t)(NN + 1) * 4);
  int*            cursor  = (int*)alloc((size_t)NN * 4);
  int*            epk     = (int*)alloc((size_t)NE * 4);

  hipMemsetAsync(countb, 0, (size_t)NN * 5 * 4, stream);
  count_kernel<<<(NE + 255) / 256, 256, 0, stream>>>(EI, eattr, countb);
  scan_kernel<<<1, 1024, 0, stream>>>(countb, rowptr, cursor);
  scatter_kernel<<<(NE + 255) / 256, 256, 0, stream>>>(EI, eattr, cursor, epk);
  init_h_kernel<<<NN, 256, 0, stream>>>(x, ntypes, ntemb, h, hb);

  dim3 tgrid(DD / 32, DD / 32);
  dim3 ggrid2(16, (NN + 127) / 128);   // dual GEMM: N=2048, 2512 blocks (%8==0)
  dim3 ggrid1(8, (NN + 127) / 128);    // final GEMM: N=1024, 1256 blocks (%8==0)
  for (int l = 0; l < 2; ++l) {
    transpose_w_kernel<<<tgrid, 256, 0, stream>>>(W_l + (size_t)l * DD * DD, WTcat);
    transpose_w_kernel<<<tgrid, 256, 0, stream>>>(W_r + (size_t)l * DD * DD, WTcat + (size_t)DD * DD);
    m_kernel<<<DD / 64, 256, 0, stream>>>(etemb, W_e + (size_t)l * DD * DD, Mbuf);
    gemm_bf16<<<ggrid2, 256, 0, stream>>>(hb, WTcat, b_l + l * DD, b_r + l * DD,
                                          xlb, xrb, nullptr, nullptr, NN, 0);
    attn_kernel<<<(NN + 3) / 4, 256, 0, stream>>>(xlb, xrb, rowptr, epk, countb, Mbuf,
                                                  att + l * DD, bias + l * DD,
                                                  gamma + l * DD, beta + l * DD, h, hb,
                                                  l == 0 ? 1 : 0);
  }
  transpose_w_kernel<<<tgrid, 256, 0, stream>>>(W_out, WT2);
  gemm_bf16<<<ggrid1, 256, 0, stream>>>(hb, WT2, b_out, nullptr,
                                        out, nullptr, x, gate, NN, 1);
}

// Round 5
// 809.807 us; speedup vs baseline: 1.1564x; 1.0840x over previous
//
#include <hip/hip_runtime.h>

// TTGNN: 2-layer GAT-style transformer conv, N=20000, E=120000, D=1024, H=8, C=128.
// R5: XCD-aware swizzle in gemm_bf16; m_kernel one-pass (all 5 types).
// R6: 4-deep gather batching — NULL (loads already pipelined).
// R7: 16-wave blocks + split h prefetch — REGRESSION (traffic + structure).
// R8: epk packed metadata (-11MB fetch, 0us) => attn NOT traffic-bound at the
//     margin; VALUBusy pinned ~35%, occ ~26% in all variants => the serial
//     ~117-op per-edge VALU chain with ~2 effective waves/SIMD is the wall.
// R9: head-parallel attn: block = 1 node = 4 waves; wave owns 2 heads
//     (4 ch/lane). Per-edge chain ~3x shorter, 4x more waves, logit reduce
//     in-wave (head = 32 lanes), LN via tiny LDS cross-wave reduce. Gather
//     rows shared by the 4 waves of a block -> L1 reuse.

#define NN 20000
#define NE 120000
#define DD 1024
#define NH 8

typedef __attribute__((ext_vector_type(4))) float f32x4;
typedef __bf16 bf16x8 __attribute__((ext_vector_type(8)));

__device__ __forceinline__ unsigned short f2bf(float f) {
  unsigned int u = __float_as_uint(f);
  u += 0x7FFFu + ((u >> 16) & 1u);   // round-to-nearest-even
  return (unsigned short)(u >> 16);
}
__device__ __forceinline__ float bf2f(unsigned short u) {
  return __uint_as_float((unsigned int)u << 16);
}
__device__ __forceinline__ void unpack8(uint4 u, float* f) {
  f[0] = __uint_as_float(u.x << 16); f[1] = __uint_as_float(u.x & 0xFFFF0000u);
  f[2] = __uint_as_float(u.y << 16); f[3] = __uint_as_float(u.y & 0xFFFF0000u);
  f[4] = __uint_as_float(u.z << 16); f[5] = __uint_as_float(u.z & 0xFFFF0000u);
  f[6] = __uint_as_float(u.w << 16); f[7] = __uint_as_float(u.w & 0xFFFF0000u);
}
__device__ __forceinline__ void unpack4(uint2 u, float* f) {
  f[0] = __uint_as_float(u.x << 16); f[1] = __uint_as_float(u.x & 0xFFFF0000u);
  f[2] = __uint_as_float(u.y << 16); f[3] = __uint_as_float(u.y & 0xFFFF0000u);
}

// ---------------- CSR build ----------------

__global__ __launch_bounds__(256) void count_kernel(
    const int* __restrict__ EI, const int* __restrict__ eattr, int* __restrict__ cnt) {
  int e = blockIdx.x * 256 + threadIdx.x;
  if (e < NE) {
    int d = EI[NE + e];
    int t = eattr[e];
    atomicAdd(&cnt[d * 5 + t], 1);
  }
}

__global__ __launch_bounds__(1024) void scan_kernel(
    const int* __restrict__ cnt, int* __restrict__ rowptr, int* __restrict__ cursor) {
  __shared__ int wsum[16];
  __shared__ int carry_s;
  int tid = threadIdx.x, lane = tid & 63, wv = tid >> 6;
  if (tid == 0) carry_s = 0;
  __syncthreads();
  for (int base = 0; base < NN; base += 1024) {
    int n = base + tid;
    int d = 0;
    if (n < NN) {
      const int* c = cnt + n * 5;
      d = c[0] + c[1] + c[2] + c[3] + c[4];
    }
    int v = d;
    #pragma unroll
    for (int off = 1; off < 64; off <<= 1) {
      int t = __shfl_up(v, off);
      if (lane >= off) v += t;
    }
    if (lane == 63) wsum[wv] = v;
    __syncthreads();
    int woff = 0;
    #pragma unroll
    for (int w = 0; w < 16; ++w) if (w < wv) woff += wsum[w];
    int carry = carry_s;
    int excl = carry + woff + v - d;
    if (n < NN) { rowptr[n] = excl; cursor[n] = excl; }
    __syncthreads();
    if (tid == 0) {
      int t = 0;
      #pragma unroll
      for (int w = 0; w < 16; ++w) t += wsum[w];
      carry_s = carry + t;
    }
    __syncthreads();
  }
  if (tid == 0) rowptr[NN] = carry_s;
}

// Writes packed (src<<3)|etype directly (reads here are coalesced).
__global__ __launch_bounds__(256) void scatter_kernel(
    const int* __restrict__ EI, const int* __restrict__ eattr,
    int* __restrict__ cursor, int* __restrict__ epk) {
  int e = blockIdx.x * 256 + threadIdx.x;
  if (e < NE) {
    int d = EI[NE + e];
    int s = EI[e];
    int t = eattr[e];
    int pos = atomicAdd(&cursor[d], 1);
    epk[pos] = (s << 3) | t;
  }
}

// ---------------- h0 = x + node_type_emb[node_types] ----------------

__global__ __launch_bounds__(256) void init_h_kernel(
    const float* __restrict__ x, const int* __restrict__ ntypes,
    const float* __restrict__ ntemb, float* __restrict__ h,
    unsigned short* __restrict__ hb) {
  int idx = blockIdx.x * 256 + threadIdx.x;
  int n = idx >> 8;
  int d4 = idx & 255;
  int t = ntypes[n];
  float4 xv = ((const float4*)x)[idx];
  float4 ev = ((const float4*)ntemb)[t * 256 + d4];
  float4 o;
  o.x = xv.x + ev.x; o.y = xv.y + ev.y; o.z = xv.z + ev.z; o.w = xv.w + ev.w;
  ((float4*)h)[idx] = o;
  ushort4 hv;
  hv.x = f2bf(o.x); hv.y = f2bf(o.y); hv.z = f2bf(o.z); hv.w = f2bf(o.w);
  ((ushort4*)hb)[idx] = hv;
}

// ---------------- weight transpose + bf16: WT[n][k] = bf16(W[k][n]) ----------------

__global__ __launch_bounds__(256) void transpose_w_kernel(
    const float* __restrict__ W, unsigned short* __restrict__ WT) {
  __shared__ float tile[32][33];
  int tx = threadIdx.x & 31, ty = threadIdx.x >> 5;
  int bx = blockIdx.x * 32;   // n base
  int by = blockIdx.y * 32;   // k base
  #pragma unroll
  for (int r = 0; r < 4; ++r)
    tile[ty + r * 8][tx] = W[(size_t)(by + ty + r * 8) * DD + bx + tx];
  __syncthreads();
  #pragma unroll
  for (int r = 0; r < 4; ++r)
    WT[(size_t)(bx + ty + r * 8) * DD + by + tx] = f2bf(tile[tx][ty + r * 8]);
}

// ---------------- M[t] = edge_type_emb[t] @ W_e[l]   (5 x 1024) ----------------

__global__ __launch_bounds__(256) void m_kernel(
    const float* __restrict__ ete, const float* __restrict__ We, float* __restrict__ M) {
  __shared__ float red[4][5][64];
  const int jl = threadIdx.x & 63;
  const int kc = threadIdx.x >> 6;          // wave-uniform
  const int j = blockIdx.x * 64 + jl;
  float acc[5] = {0.f, 0.f, 0.f, 0.f, 0.f};
  const int k0 = kc * 256;
  for (int k = k0; k < k0 + 256; ++k) {
    float w = We[(size_t)k * DD + j];
    #pragma unroll
    for (int t = 0; t < 5; ++t) acc[t] += ete[t * DD + k] * w;
  }
  #pragma unroll
  for (int t = 0; t < 5; ++t) red[kc][t][jl] = acc[t];
  __syncthreads();
  if (threadIdx.x < 64) {
    #pragma unroll
    for (int t = 0; t < 5; ++t)
      M[t * DD + blockIdx.x * 64 + threadIdx.x] =
          red[0][t][threadIdx.x] + red[1][t][threadIdx.x] +
          red[2][t][threadIdx.x] + red[3][t][threadIdx.x];
  }
}

// ---------------- bf16 MFMA GEMM, global_load_lds staging (m97 structure) ----

__global__ __launch_bounds__(256) void gemm_bf16(
    const unsigned short* __restrict__ A, const unsigned short* __restrict__ BT,
    const float* __restrict__ bias0, const float* __restrict__ bias1,
    void* __restrict__ C0v, void* __restrict__ C1v,
    const float* __restrict__ resid, const float* __restrict__ gatep,
    int M, int mode) {
  __shared__ unsigned short lsA[128 * 32];
  __shared__ unsigned short lsB[128 * 32];
  const int tid = threadIdx.x;
  const int lane = tid & 63;
  const int wv = tid >> 6;
  const int wm = wv & 1, wn = wv >> 1;

  // T1: XCD swizzle. nwg % 8 == 0 for both launch shapes (2512, 1256).
  const int nwg = gridDim.x * gridDim.y;
  const int lid = blockIdx.y * gridDim.x + blockIdx.x;
  const int cpx = nwg >> 3;
  const int swz = (lid & 7) * cpx + (lid >> 3);
  const int bm = swz / gridDim.x, bn = swz % gridDim.x;

  const int row0 = bm * 128, col0 = bn * 128;
  const int l15 = lane & 15, quad = lane >> 4;

  f32x4 acc[4][4];
  #pragma unroll
  for (int mt = 0; mt < 4; ++mt)
    #pragma unroll
    for (int nt = 0; nt < 4; ++nt) {
      f32x4 z = {0.f, 0.f, 0.f, 0.f};
      acc[mt][nt] = z;
    }

  const int r_in = lane >> 2;            // 0..15
  const int kchunk = (lane & 3) * 8;     // bf16-element offset within 32-wide K

  for (int kk = 0; kk < DD; kk += 32) {
    #pragma unroll
    for (int j = 0; j < 2; ++j) {
      int r = wv * 32 + j * 16;                  // wave-uniform row base
      int gr = row0 + r + r_in;
      if (gr > M - 1) gr = M - 1;                // clamp tail (masked at store)
      const unsigned short* gpA = A + (size_t)gr * DD + kk + kchunk;
      __builtin_amdgcn_global_load_lds(
          (const __attribute__((address_space(1))) unsigned int*)gpA,
          (__attribute__((address_space(3))) unsigned int*)(lsA + r * 32), 16, 0, 0);
      const unsigned short* gpB = BT + (size_t)(col0 + r + r_in) * DD + kk + kchunk;
      __builtin_amdgcn_global_load_lds(
          (const __attribute__((address_space(1))) unsigned int*)gpB,
          (__attribute__((address_space(3))) unsigned int*)(lsB + r * 32), 16, 0, 0);
    }
    __syncthreads();
    bf16x8 af[4], bfr[4];
    #pragma unroll
    for (int mt = 0; mt < 4; ++mt)
      af[mt] = *(const bf16x8*)(lsA + (wm * 64 + mt * 16 + l15) * 32 + quad * 8);
    #pragma unroll
    for (int nt = 0; nt < 4; ++nt)
      bfr[nt] = *(const bf16x8*)(lsB + (wn * 64 + nt * 16 + l15) * 32 + quad * 8);
    #pragma unroll
    for (int mt = 0; mt < 4; ++mt)
      #pragma unroll
      for (int nt = 0; nt < 4; ++nt)
        acc[mt][nt] = __builtin_amdgcn_mfma_f32_16x16x32_bf16(af[mt], bfr[nt], acc[mt][nt], 0, 0, 0);
    __syncthreads();
  }

  if (mode == 0) {
    unsigned short* Cb = (unsigned short*)(bn < 8 ? C0v : C1v);
    const float* bp = (bn < 8) ? bias0 : bias1;
    int coff = (bn < 8) ? 0 : 1024;
    #pragma unroll
    for (int mt = 0; mt < 4; ++mt) {
      #pragma unroll
      for (int r = 0; r < 4; ++r) {
        int grow = row0 + wm * 64 + mt * 16 + quad * 4 + r;
        if (grow >= M) continue;
        #pragma unroll
        for (int nt = 0; nt < 4; ++nt) {
          int c = col0 - coff + wn * 64 + nt * 16 + l15;
          Cb[(size_t)grow * DD + c] = f2bf(acc[mt][nt][r] + bp[c]);
        }
      }
    }
  } else {
    float* Cp = (float*)C0v;
    float g = gatep[0];
    #pragma unroll
    for (int mt = 0; mt < 4; ++mt) {
      #pragma unroll
      for (int r = 0; r < 4; ++r) {
        int grow = row0 + wm * 64 + mt * 16 + quad * 4 + r;
        if (grow >= M) continue;
        #pragma unroll
        for (int nt = 0; nt < 4; ++nt) {
          int c = col0 + wn * 64 + nt * 16 + l15;
          float v = acc[mt][nt][r] + bias0[c];
          Cp[(size_t)grow * DD + c] = resid[(size_t)grow * DD + c] + g * v;
        }
      }
    }
  }
}

// ---------------- fused attention, head-parallel (R9) ----------------
// Block = 256 threads = 1 node = 4 waves; wave wv owns channels
// [wv*256, wv*256+256) = heads 2wv, 2wv+1; lane owns 4 channels
// (ch = wv*256 + lane*4). Lanes 0-31 of a wave are in head 2wv, lanes 32-63
// in head 2wv+1 (xor-masks < 32 never cross the half, so the 5-step xor
// reduce yields the per-head logit on all 32 lanes of that head).
// Softmax without max-subtraction (shift-invariant; logits bounded).
// LayerNorm: per-wave partial moments + 4-slot LDS cross-wave reduce.

__global__ __launch_bounds__(256) void attn_kernel(
    const unsigned short* __restrict__ xlb, const unsigned short* __restrict__ xrb,
    const int* __restrict__ rowptr, const int* __restrict__ epk,
    const int* __restrict__ cnt, const float* __restrict__ Mbuf,
    const float* __restrict__ attl, const float* __restrict__ biasl,
    const float* __restrict__ gammal, const float* __restrict__ betal,
    float* __restrict__ h, unsigned short* __restrict__ hb, int write_h) {
  __shared__ float red1[4], red2[4];
  const int lane = threadIdx.x & 63;
  const int wv = threadIdx.x >> 6;
  const int n = blockIdx.x;
  const int ch = wv * 256 + lane * 4;

  const int beg = rowptr[n], end = rowptr[n + 1];
  const int* c5 = cnt + n * 5;
  int c0 = c5[0], c1 = c5[1], c2 = c5[2], c3 = c5[3], c4 = c5[4];

  float xrf[4], attf[4];
  {
    uint2 a = *(const uint2*)(xrb + (size_t)n * DD + ch);
    unpack4(a, xrf);
    float4 t = *(const float4*)(attl + ch);
    attf[0] = t.x; attf[1] = t.y; attf[2] = t.z; attf[3] = t.w;
  }
  float acc0 = 0.f, acc1 = 0.f, acc2 = 0.f, acc3 = 0.f;
  float den = 0.f;

  for (int base = beg; base < end; base += 64) {
    int cc = min(64, end - base);
    int packed = 0;
    if (lane < cc) packed = epk[base + lane];
    for (int j = 0; j < cc; ++j) {
      int pk = __shfl(packed, j);
      int src = pk >> 3, at = pk & 7;
      uint2 v = *(const uint2*)(xlb + (size_t)src * DD + ch);
      float4 m = *(const float4*)(Mbuf + at * DD + ch);
      float vf[4];
      unpack4(v, vf);
      float s0 = vf[0] + xrf[0] + m.x; s0 = fmaxf(s0, 0.2f * s0);
      float s1 = vf[1] + xrf[1] + m.y; s1 = fmaxf(s1, 0.2f * s1);
      float s2 = vf[2] + xrf[2] + m.z; s2 = fmaxf(s2, 0.2f * s2);
      float s3 = vf[3] + xrf[3] + m.w; s3 = fmaxf(s3, 0.2f * s3);
      float lg = s0 * attf[0] + s1 * attf[1] + s2 * attf[2] + s3 * attf[3];
      lg += __shfl_xor(lg, 1);
      lg += __shfl_xor(lg, 2);
      lg += __shfl_xor(lg, 4);
      lg += __shfl_xor(lg, 8);
      lg += __shfl_xor(lg, 16);
      float p = __expf(lg);
      den += p;
      acc0 += p * vf[0]; acc1 += p * vf[1];
      acc2 += p * vf[2]; acc3 += p * vf[3];
    }
  }

  // self-loop: edge emb = mean of incoming edge-type embeddings
  {
    float inv = 1.f / fmaxf((float)(c0 + c1 + c2 + c3 + c4), 1.f);
    float w0 = c0 * inv, w1 = c1 * inv, w2 = c2 * inv, w3 = c3 * inv, w4 = c4 * inv;
    uint2 v = *(const uint2*)(xlb + (size_t)n * DD + ch);
    float vf[4];
    unpack4(v, vf);
    float4 m0 = *(const float4*)(Mbuf + 0 * DD + ch);
    float4 m1 = *(const float4*)(Mbuf + 1 * DD + ch);
    float4 m2 = *(const float4*)(Mbuf + 2 * DD + ch);
    float4 m3 = *(const float4*)(Mbuf + 3 * DD + ch);
    float4 m4 = *(const float4*)(Mbuf + 4 * DD + ch);
    float e0 = w0 * m0.x + w1 * m1.x + w2 * m2.x + w3 * m3.x + w4 * m4.x;
    float e1 = w0 * m0.y + w1 * m1.y + w2 * m2.y + w3 * m3.y + w4 * m4.y;
    float e2 = w0 * m0.z + w1 * m1.z + w2 * m2.z + w3 * m3.z + w4 * m4.z;
    float e3 = w0 * m0.w + w1 * m1.w + w2 * m2.w + w3 * m3.w + w4 * m4.w;
    float s0 = vf[0] + xrf[0] + e0; s0 = fmaxf(s0, 0.2f * s0);
    float s1 = vf[1] + xrf[1] + e1; s1 = fmaxf(s1, 0.2f * s1);
    float s2 = vf[2] + xrf[2] + e2; s2 = fmaxf(s2, 0.2f * s2);
    float s3 = vf[3] + xrf[3] + e3; s3 = fmaxf(s3, 0.2f * s3);
    float lg = s0 * attf[0] + s1 * attf[1] + s2 * attf[2] + s3 * attf[3];
    lg += __shfl_xor(lg, 1);
    lg += __shfl_xor(lg, 2);
    lg += __shfl_xor(lg, 4);
    lg += __shfl_xor(lg, 8);
    lg += __shfl_xor(lg, 16);
    float p = __expf(lg);
    den += p;
    acc0 += p * vf[0]; acc1 += p * vf[1];
    acc2 += p * vf[2]; acc3 += p * vf[3];
  }

  // epilogue: alpha-normalize + bias + ELU + residual + LayerNorm (cross-wave)
  float invd = 1.f / den;
  float4 b4 = *(const float4*)(biasl + ch);
  float4 h4 = *(const float4*)(h + (size_t)n * DD + ch);
  float o0 = acc0 * invd + b4.x;
  float o1 = acc1 * invd + b4.y;
  float o2 = acc2 * invd + b4.z;
  float o3 = acc3 * invd + b4.w;
  o0 = o0 > 0.f ? o0 : (__expf(o0) - 1.f);
  o1 = o1 > 0.f ? o1 : (__expf(o1) - 1.f);
  o2 = o2 > 0.f ? o2 : (__expf(o2) - 1.f);
  o3 = o3 > 0.f ? o3 : (__expf(o3) - 1.f);
  float y0 = o0 + h4.x, y1 = o1 + h4.y, y2 = o2 + h4.z, y3 = o3 + h4.w;
  float s1r = y0 + y1 + y2 + y3;
  float s2r = y0 * y0 + y1 * y1 + y2 * y2 + y3 * y3;
  #pragma unroll
  for (int off = 1; off < 64; off <<= 1) {
    s1r += __shfl_xor(s1r, off);
    s2r += __shfl_xor(s2r, off);
  }
  if (lane == 0) { red1[wv] = s1r; red2[wv] = s2r; }
  __syncthreads();
  float t1 = red1[0] + red1[1] + red1[2] + red1[3];
  float t2 = red2[0] + red2[1] + red2[2] + red2[3];
  float mu = t1 * (1.f / 1024.f);
  float var = t2 * (1.f / 1024.f) - mu * mu;
  float rs = rsqrtf(var + 1e-5f);
  {
    float4 g4 = *(const float4*)(gammal + ch);
    float4 be4 = *(const float4*)(betal + ch);
    float w0 = (y0 - mu) * rs * g4.x + be4.x;
    float w1 = (y1 - mu) * rs * g4.y + be4.y;
    float w2 = (y2 - mu) * rs * g4.z + be4.z;
    float w3 = (y3 - mu) * rs * g4.w + be4.w;
    if (write_h) {
      float4 o4; o4.x = w0; o4.y = w1; o4.z = w2; o4.w = w3;
      *(float4*)(h + (size_t)n * DD + ch) = o4;
    }
    uint2 pk;
    pk.x = (unsigned int)f2bf(w0) | ((unsigned int)f2bf(w1) << 16);
    pk.y = (unsigned int)f2bf(w2) | ((unsigned int)f2bf(w3) << 16);
    *(uint2*)(hb + (size_t)n * DD + ch) = pk;
  }
}

// ---------------- launcher ----------------

extern "C" void kernel_launch(void* const* d_in, const int* in_sizes, int n_in,
                              void* d_out, int out_size, void* d_ws, size_t ws_size,
                              hipStream_t stream) {
  (void)in_sizes; (void)n_in; (void)out_size; (void)ws_size;
  const float* x      = (const float*)d_in[0];
  const int*   EI     = (const int*)d_in[1];
  const int*   eattr  = (const int*)d_in[2];
  const int*   ntypes = (const int*)d_in[3];
  const float* ntemb  = (const float*)d_in[4];
  const float* etemb  = (const float*)d_in[5];
  const float* W_l    = (const float*)d_in[6];
  const float* b_l    = (const float*)d_in[7];
  const float* W_r    = (const float*)d_in[8];
  const float* b_r    = (const float*)d_in[9];
  const float* W_e    = (const float*)d_in[10];
  const float* att    = (const float*)d_in[11];
  const float* bias   = (const float*)d_in[12];
  const float* gamma  = (const float*)d_in[13];
  const float* beta   = (const float*)d_in[14];
  const float* W_out  = (const float*)d_in[15];
  const float* b_out  = (const float*)d_in[16];
  const float* gate   = (const float*)d_in[17];
  float* out = (float*)d_out;

  char* ws = (char*)d_ws;
  size_t off = 0;
  auto alloc = [&](size_t bytes) {
    char* p = ws + off;
    off = (off + bytes + 255) & ~(size_t)255;
    return p;
  };
  float*          h       = (float*)alloc((size_t)NN * DD * 4);
  unsigned short* hb      = (unsigned short*)alloc((size_t)NN * DD * 2);
  unsigned short* xlb     = (unsigned short*)alloc((size_t)NN * DD * 2);
  unsigned short* xrb     = (unsigned short*)alloc((size_t)NN * DD * 2);
  unsigned short* WTcat   = (unsigned short*)alloc((size_t)2 * DD * DD * 2);  // [W_l^T ; W_r^T]
  unsigned short* WT2     = (unsigned short*)alloc((size_t)DD * DD * 2);
  float*          Mbuf    = (float*)alloc((size_t)5 * DD * 4);
  int*            countb  = (int*)alloc((size_t)NN * 5 * 4);
  int*            rowptr  = (int*)alloc((size_t)(NN + 1) * 4);
  int*            cursor  = (int*)alloc((size_t)NN * 4);
  int*            epk     = (int*)alloc((size_t)NE * 4);

  hipMemsetAsync(countb, 0, (size_t)NN * 5 * 4, stream);
  count_kernel<<<(NE + 255) / 256, 256, 0, stream>>>(EI, eattr, countb);
  scan_kernel<<<1, 1024, 0, stream>>>(countb, rowptr, cursor);
  scatter_kernel<<<(NE + 255) / 256, 256, 0, stream>>>(EI, eattr, cursor, epk);
  init_h_kernel<<<NN, 256, 0, stream>>>(x, ntypes, ntemb, h, hb);

  dim3 tgrid(DD / 32, DD / 32);
  dim3 ggrid2(16, (NN + 127) / 128);   // dual GEMM: N=2048, 2512 blocks (%8==0)
  dim3 ggrid1(8, (NN + 127) / 128);    // final GEMM: N=1024, 1256 blocks (%8==0)
  for (int l = 0; l < 2; ++l) {
    transpose_w_kernel<<<tgrid, 256, 0, stream>>>(W_l + (size_t)l * DD * DD, WTcat);
    transpose_w_kernel<<<tgrid, 256, 0, stream>>>(W_r + (size_t)l * DD * DD, WTcat + (size_t)DD * DD);
    m_kernel<<<DD / 64, 256, 0, stream>>>(etemb, W_e + (size_t)l * DD * DD, Mbuf);
    gemm_bf16<<<ggrid2, 256, 0, stream>>>(hb, WTcat, b_l + l * DD, b_r + l * DD,
                                          xlb, xrb, nullptr, nullptr, NN, 0);
    attn_kernel<<<NN, 256, 0, stream>>>(xlb, xrb, rowptr, epk, countb, Mbuf,
                                        att + l * DD, bias + l * DD,
                                        gamma + l * DD, beta + l * DD, h, hb,
                                        l == 0 ? 1 : 0);
  }
  transpose_w_kernel<<<tgrid, 256, 0, stream>>>(W_out, WT2);
  gemm_bf16<<<ggrid1, 256, 0, stream>>>(hb, WT2, b_out, nullptr,
                                        out, nullptr, x, gate, NN, 1);
}